// Round 5
// baseline (104.393 us; speedup 1.0000x reference)
//
#include <hip/hip_runtime.h>
#include <hip/hip_fp16.h>
#include <math.h>

#define NCLUS 56
#define HH 224
#define WW 224
#define BB 32
#define CELLS (NCLUS * NCLUS) /* 3136 */
#define HW (HH * WW)

typedef float f32x4 __attribute__((ext_vector_type(4)));

// ---------------------------------------------------------------------------
// Kernel A: Sobel -> grad mag -> inverted -> 4x4 mean pool. (unchanged)
// ---------------------------------------------------------------------------
__global__ __launch_bounds__(256) void pool_kernel(const float* __restrict__ cf,
                                                   float* __restrict__ pooled) {
    __shared__ float lds[18][226];
    int b = blockIdx.x / 14;
    int grp = blockIdx.x - b * 14;
    int tid = threadIdx.x;
    const float* e = cf + ((size_t)b * 65 + 64) * HW;

    int y0 = grp * 16 - 1;
    for (int t = tid; t < 18 * 224; t += 256) {
        int r = t / 224;
        int c = t - r * 224;
        int y = y0 + r;
        lds[r][c + 1] = (y >= 0 && y < HH) ? e[y * WW + c] : 0.0f;
    }
    if (tid < 18) { lds[tid][0] = 0.0f; lds[tid][225] = 0.0f; }
    __syncthreads();

    if (tid >= 224) return;
    int lby = tid / 56;
    int bx = tid - lby * 56;
    int r0 = lby * 4;
    int c0 = bx * 4;

    float patch[6][6];
#pragma unroll
    for (int i = 0; i < 6; ++i)
#pragma unroll
        for (int j = 0; j < 6; ++j) patch[i][j] = lds[r0 + i][c0 + j];

    float s = 0.0f;
#pragma unroll
    for (int iy = 0; iy < 4; ++iy) {
#pragma unroll
        for (int ix = 0; ix < 4; ++ix) {
            float gx = (patch[iy][ix + 2] - patch[iy][ix])
                     + 2.0f * (patch[iy + 1][ix + 2] - patch[iy + 1][ix])
                     + (patch[iy + 2][ix + 2] - patch[iy + 2][ix]);
            float gy = (patch[iy + 2][ix] - patch[iy][ix])
                     + 2.0f * (patch[iy + 2][ix + 1] - patch[iy][ix + 1])
                     + (patch[iy + 2][ix + 2] - patch[iy][ix + 2]);
            float gm = sqrtf(gx * gx + gy * gy);
            s += 1.0f - 0.5f * gm;
        }
    }
    pooled[b * CELLS + (grp * 4 + lby) * NCLUS + bx] = s * 0.0625f;
}

// ---------------------------------------------------------------------------
// Kernel B: per-batch top-56 via radix select + rank sort. (unchanged)
// ---------------------------------------------------------------------------
__global__ __launch_bounds__(256) void topk_kernel(
        const float* __restrict__ pooled,
        float* __restrict__ sy, float* __restrict__ sx) {
    int b = blockIdx.x;
    int tid = threadIdx.x;
    __shared__ unsigned long long list[CELLS];
    __shared__ unsigned nlist_s;
    if (tid == 0) nlist_s = 0;

    if (tid < 64) {
        unsigned hi[49];
#pragma unroll
        for (int j = 0; j < 49; ++j) {
            int i = j * 64 + tid;
            unsigned u = __float_as_uint(pooled[b * CELLS + i]);
            hi[j] = (u & 0x80000000u) ? ~u : (u | 0x80000000u);
        }
        unsigned prefix = 0;
        unsigned cnt = CELLS;
        for (int bit = 31; bit >= 0; --bit) {
            if (cnt <= 448u) break;
            unsigned cand = prefix | (1u << bit);
            unsigned c = 0;
#pragma unroll
            for (int j = 0; j < 49; ++j) c += (hi[j] >= cand) ? 1u : 0u;
#pragma unroll
            for (int off = 32; off >= 1; off >>= 1)
                c += __shfl_xor(c, off, 64);
            if (c >= (unsigned)NCLUS) { prefix = cand; cnt = c; } // uniform
        }
#pragma unroll
        for (int j = 0; j < 49; ++j) {
            if (hi[j] >= prefix) {
                unsigned pos = atomicAdd(&nlist_s, 1u);
                unsigned i = (unsigned)(j * 64 + tid);
                list[pos] = ((unsigned long long)hi[j] << 32) |
                            (unsigned long long)(0xFFFFFFFFu - i);
            }
        }
    }
    __syncthreads();

    int N = (int)nlist_s;
    for (int c = tid; c < N; c += 256) {
        unsigned long long key = list[c];
        int r = 0;
        for (int j = 0; j < N; ++j) r += (list[j] > key) ? 1 : 0;
        if (r < NCLUS) {
            unsigned idx = 0xFFFFFFFFu - (unsigned)(key & 0xFFFFFFFFull);
            sy[b * NCLUS + r] = (float)(idx / NCLUS) / (float)NCLUS;
            sx[b * NCLUS + r] = (float)(idx % NCLUS) / (float)NCLUS;
        }
    }
}

// ---------------------------------------------------------------------------
// Kernel C: fused tables + factored softmax.
// Changes vs round 4 (testing two store-side hypotheses at once):
//   * Fx table in LDS as fp16 (25KB) -> block LDS 26.9KB -> 4 blocks/CU
//     (was 3), smoother 3.5-blocks/CU tail, more store-issue parallelism.
//     fx in [1,1.649] so fp16 rel err 2^-11 -> output err += ~1e-4, safe.
//   * Regular stores (NT hint removed) -- the 6.9TB/s fill reference goes
//     through L2; NT bypass is unproven and is suspect #1 for the 4TB/s
//     effective write BW.
// ---------------------------------------------------------------------------
__global__ __launch_bounds__(448) void markers_kernel(
        const float* __restrict__ sy, const float* __restrict__ sx,
        const float* __restrict__ stdp, float* __restrict__ out) {
    __shared__ __half2 fx_h[NCLUS][WW / 2]; // 25,088 B
    __shared__ float fy_s[8 * NCLUS];       //  1,792 B
    int blk = blockIdx.x;
    int b = blk / 28;
    int h0 = (blk - b * 28) * 8;
    int tid = threadIdx.x;
    float inv_std = 1.0f / stdp[0];
    const float* syb = sy + b * NCLUS;
    const float* sxb = sx + b * NCLUS;

    // Fx table: 12544 entries = 28 per thread, w-contiguous LDS writes.
    for (int t = tid; t < NCLUS * WW; t += 448) {
        int k = t / WW;
        int w = t - k * WW;
        float tx = ((float)w / 224.0f - sxb[k]) * inv_std;
        float v = expf(0.5f * expf(-(tx * tx)));
        ((__half*)fx_h)[k * WW + w] = __float2half_rn(v);
    }
    // fy: exactly one entry per thread (448 = 8 rows x 56 k).
    {
        int row = tid / NCLUS;
        int k = tid - row * NCLUS;
        float ty = ((float)(h0 + row) / 224.0f - syb[k]) * inv_std;
        fy_s[tid] = expf(0.5f * expf(-(ty * ty)));
    }
    __syncthreads();

    int row = tid / 56;      // 0..7
    int wq = tid - row * 56; // 0..55 -> w = 4*wq
    const float* fyp = fy_s + row * NCLUS;

    float s0 = 0.f, s1 = 0.f, s2 = 0.f, s3 = 0.f;
#pragma unroll 8
    for (int k = 0; k < NCLUS; ++k) {
        float fy = fyp[k];
        union { uint2 u; __half2 h[2]; } v;
        v.u = *(const uint2*)&fx_h[k][wq * 2];
        float2 f0 = __half22float2(v.h[0]);
        float2 f1 = __half22float2(v.h[1]);
        s0 = fmaf(fy, f0.x, s0);
        s1 = fmaf(fy, f0.y, s1);
        s2 = fmaf(fy, f1.x, s2);
        s3 = fmaf(fy, f1.y, s3);
    }
    float r0 = 1.0f / s0, r1 = 1.0f / s1, r2 = 1.0f / s2, r3 = 1.0f / s3;

    float* op = out + (size_t)b * NCLUS * HW + (size_t)(h0 + row) * WW + wq * 4;
#pragma unroll 8
    for (int k = 0; k < NCLUS; ++k) {
        float fy = fyp[k];
        union { uint2 u; __half2 h[2]; } v;
        v.u = *(const uint2*)&fx_h[k][wq * 2];
        float2 f0 = __half22float2(v.h[0]);
        float2 f1 = __half22float2(v.h[1]);
        f32x4 o;
        o.x = (fy * f0.x) * r0;
        o.y = (fy * f0.y) * r1;
        o.z = (fy * f1.x) * r2;
        o.w = (fy * f1.y) * r3;
        *(f32x4*)op = o;
        op += HW;
    }
}

// ---------------------------------------------------------------------------
extern "C" void kernel_launch(void* const* d_in, const int* in_sizes, int n_in,
                              void* d_out, int out_size, void* d_ws,
                              size_t ws_size, hipStream_t stream) {
    const float* cf = (const float*)d_in[0];   // (32, 65, 224, 224) f32
    const float* stdp = (const float*)d_in[1]; // scalar f32
    float* out = (float*)d_out;                // (32, 56, 224, 224) f32

    char* ws = (char*)d_ws;
    float* pooled = (float*)ws;                    // 401 KB
    float* sy = (float*)(ws + 512 * 1024);         // 7 KB
    float* sx = (float*)(ws + 576 * 1024);         // 7 KB

    pool_kernel<<<BB * 14, 256, 0, stream>>>(cf, pooled);
    topk_kernel<<<BB, 256, 0, stream>>>(pooled, sy, sx);
    markers_kernel<<<BB * 28, 448, 0, stream>>>(sy, sx, stdp, out);
}